// Round 1
// baseline (248.731 us; speedup 1.0000x reference)
//
#include <hip/hip_runtime.h>

#define D 32          // feature dim (fixed for this problem)
#define BLK 256       // threads per block

// ---------------------------------------------------------------------------
// Kernel P: per-row precompute.
//   xp[r]  = float4(20*px, 20*py, 20*pz, |20*p|^2)   (x = points / SIGMA)
//   f1n[r] = |fea1_r|^2,  f2n[r] = |fea2_r|^2
// ---------------------------------------------------------------------------
__global__ __launch_bounds__(BLK) void precompute_kernel(
    const float* __restrict__ points,
    const float* __restrict__ fea1,
    const float* __restrict__ fea2,
    float4* __restrict__ xp,
    float* __restrict__ f1n,
    float* __restrict__ f2n,
    int BN)
{
    int r = blockIdx.x * BLK + threadIdx.x;
    if (r >= BN) return;
    const float s = 20.0f;  // 1 / SIGMA, SIGMA = 0.05
    float x = points[3*r+0] * s;
    float y = points[3*r+1] * s;
    float z = points[3*r+2] * s;
    float4 v; v.x = x; v.y = y; v.z = z; v.w = x*x + y*y + z*z;
    xp[r] = v;

    const float4* p1 = (const float4*)(fea1 + (size_t)r * D);
    const float4* p2 = (const float4*)(fea2 + (size_t)r * D);
    float n1 = 0.f, n2 = 0.f;
#pragma unroll
    for (int k = 0; k < D/4; ++k) {
        float4 a = p1[k];
        float4 b = p2[k];
        n1 = fmaf(a.x,a.x, fmaf(a.y,a.y, fmaf(a.z,a.z, fmaf(a.w,a.w, n1))));
        n2 = fmaf(b.x,b.x, fmaf(b.y,b.y, fmaf(b.z,b.z, fmaf(b.w,b.w, n2))));
    }
    f1n[r] = n1;
    f2n[r] = n2;
}

// ---------------------------------------------------------------------------
// Kernel A: the pair loop.  One thread per row i (lane-parallel rows, so the
// per-j data -- fea2 row, xj, |fea2_j|^2 -- is wave-uniform and eligible for
// the scalar-load path).  Each block handles 256 rows x one j-chunk of JC.
// Accumulates 5 per-row sums (shift m=0 is numerically safe: all logits <= 0,
// dominant feature term >= e^{-80} which is a normal fp32), combined across
// chunks with float atomics.
//   acc layout: [A | S2a | B | S2b | Sab], each BN floats.
// ---------------------------------------------------------------------------
__global__ __launch_bounds__(BLK) void pair_kernel(
    const float* __restrict__ fea1,
    const float* __restrict__ fea2,
    const float4* __restrict__ xp,
    const float* __restrict__ f1n,
    const float* __restrict__ f2n,
    float* __restrict__ acc,
    int N, int JC, int BN)
{
    int row = blockIdx.x * BLK + threadIdx.x;   // global row in [0, BN)
    int b   = row / N;                          // batch index (uniform per block)

    float4 xi  = xp[row];
    float  fi2 = f1n[row];

    // fea1 row -> 32 VGPRs
    float f1r[D];
    const float4* f1v = (const float4*)(fea1 + (size_t)row * D);
#pragma unroll
    for (int k = 0; k < D/4; ++k) {
        float4 t = f1v[k];
        f1r[4*k+0] = t.x; f1r[4*k+1] = t.y; f1r[4*k+2] = t.z; f1r[4*k+3] = t.w;
    }

    float sA = 0.f, s2a = 0.f, sB = 0.f, s2b = 0.f, sab = 0.f;

    int j0 = blockIdx.y * JC;
    const float*  f2b  = fea2 + (size_t)b * N * D;
    const float4* xpb  = xp  + (size_t)b * N;
    const float*  f2nb = f2n + (size_t)b * N;

#pragma unroll 2
    for (int jj = 0; jj < JC; ++jj) {
        int j = j0 + jj;                        // wave-uniform
        const float4* f2v = (const float4*)(f2b + (size_t)j * D);

        // feature dot with 4 parallel accumulators (break the FMA chain)
        float da = 0.f, db = 0.f, dc = 0.f, dd = 0.f;
#pragma unroll
        for (int k = 0; k < D/4; ++k) {
            float4 q = f2v[k];
            da = fmaf(f1r[4*k+0], q.x, da);
            db = fmaf(f1r[4*k+1], q.y, db);
            dc = fmaf(f1r[4*k+2], q.z, dc);
            dd = fmaf(f1r[4*k+3], q.w, dd);
        }
        float dot = (da + db) + (dc + dd);

        float4 xj = xpb[j];
        float dx = fmaf(xi.x, xj.x, fmaf(xi.y, xj.y, xi.z * xj.z));

        float a  = (dx + dx)  - xi.w - xj.w;    // -dist_pts(i,j)   (<= ~0)
        float bt = (dot + dot) - fi2 - f2nb[j]; // -dist_fea(i,j)   (<= ~0)

        float ea = __expf(a);
        float eb = __expf(bt);

        sA += ea;
        sB += eb;
        s2a = fmaf(ea, ea, s2a);
        s2b = fmaf(eb, eb, s2b);
        sab = fmaf(ea, eb, sab);
    }

    atomicAdd(&acc[0*BN + row], sA);
    atomicAdd(&acc[1*BN + row], s2a);
    atomicAdd(&acc[2*BN + row], sB);
    atomicAdd(&acc[3*BN + row], s2b);
    atomicAdd(&acc[4*BN + row], sab);
}

// ---------------------------------------------------------------------------
// Kernel B: per-row combine + batch reduction.  One block per batch.
//   out[b] = sum_i w_i * ( S2a/A^2 - 2*Sab/(A*B) + S2b/B^2 )
// ---------------------------------------------------------------------------
__global__ __launch_bounds__(BLK) void finalize_kernel(
    const float* __restrict__ acc,
    const float* __restrict__ weights,
    float* __restrict__ out,
    int N, int BN)
{
    int b = blockIdx.x;
    float sum = 0.f;
    for (int t = threadIdx.x; t < N; t += BLK) {
        int row = b * N + t;
        float A   = acc[0*BN + row];
        float S2a = acc[1*BN + row];
        float Bt  = acc[2*BN + row];
        float S2b = acc[3*BN + row];
        float Sab = acc[4*BN + row];
        float invA = 1.0f / A;        // A >= 1 (contains the j=i term)
        float invB = 1.0f / Bt;       // Bt > 0 (dominant term is fp32-normal)
        float val = S2a*invA*invA - 2.0f*Sab*invA*invB + S2b*invB*invB;
        sum = fmaf(weights[row], val, sum);
    }
    // block reduction (wave=64 shuffle, then LDS across the 4 waves)
    __shared__ float red[BLK/64];
    for (int off = 32; off > 0; off >>= 1)
        sum += __shfl_down(sum, off);
    if ((threadIdx.x & 63) == 0) red[threadIdx.x >> 6] = sum;
    __syncthreads();
    if (threadIdx.x == 0) {
        float s = 0.f;
#pragma unroll
        for (int w = 0; w < BLK/64; ++w) s += red[w];
        out[b] = s;
    }
}

// ---------------------------------------------------------------------------
extern "C" void kernel_launch(void* const* d_in, const int* in_sizes, int n_in,
                              void* d_out, int out_size, void* d_ws, size_t ws_size,
                              hipStream_t stream) {
    const float* points  = (const float*)d_in[0];
    const float* fea1    = (const float*)d_in[1];
    const float* fea2    = (const float*)d_in[2];
    const float* weights = (const float*)d_in[3];
    float* out = (float*)d_out;

    int B  = out_size;          // 2
    int BN = in_sizes[3];       // B*N = 8192
    int N  = BN / B;            // 4096

    // workspace layout (floats):
    //   [0, 5*BN)            : acc  (A, S2a, B, S2b, Sab)
    //   [5*BN, 9*BN)         : xp   (float4 per row)
    //   [9*BN, 10*BN)        : f2n
    //   [10*BN, 11*BN)       : f1n
    float*  acc = (float*)d_ws;
    float4* xp  = (float4*)((char*)d_ws + (size_t)5 * BN * sizeof(float));
    float*  f2n = (float*)((char*)d_ws + (size_t)9 * BN * sizeof(float));
    float*  f1n = (float*)((char*)d_ws + (size_t)10 * BN * sizeof(float));

    hipMemsetAsync(acc, 0, (size_t)5 * BN * sizeof(float), stream);

    precompute_kernel<<<dim3((BN + BLK - 1) / BLK), dim3(BLK), 0, stream>>>(
        points, fea1, fea2, xp, f1n, f2n, BN);

    const int CH = 32;          // j-chunks per row  -> 32x32 = 1024 blocks
    int JC = N / CH;            // 128 j's per chunk
    dim3 grid(BN / BLK, CH);
    pair_kernel<<<grid, dim3(BLK), 0, stream>>>(
        fea1, fea2, xp, f1n, f2n, acc, N, JC, BN);

    finalize_kernel<<<dim3(B), dim3(BLK), 0, stream>>>(acc, weights, out, N, BN);
}

// Round 2
// 107.852 us; speedup vs baseline: 2.3062x; 2.3062x over previous
//
#include <hip/hip_runtime.h>

#define D   32        // feature dim (fixed)
#define BLK 256       // threads per block
#define JC  64        // j-chunk per block (N/JC = 64 chunks)

typedef float v2f __attribute__((ext_vector_type(2)));

#ifndef LOG2E
#define LOG2E 1.44269504088896340736f
#endif

// ---------------------------------------------------------------------------
// Kernel P: per-row precompute + zero-init of acc and out.
//   xp[r]  = (20*px, 20*py, 20*pz, log2e*|20*p|^2)     (w pre-scaled by log2e)
//   f1n[r] = log2e*|fea1_r|^2,  f2n[r] = log2e*|fea2_r|^2
// ---------------------------------------------------------------------------
__global__ __launch_bounds__(BLK) void precompute_kernel(
    const float* __restrict__ points,
    const float* __restrict__ fea1,
    const float* __restrict__ fea2,
    float4* __restrict__ xp,
    float* __restrict__ f1n,
    float* __restrict__ f2n,
    float* __restrict__ acc,
    float* __restrict__ out,
    int BN, int Bsz)
{
    int r = blockIdx.x * BLK + threadIdx.x;
    if (r < Bsz) out[r] = 0.0f;                 // zero the output (atomics later)
    if (r >= BN) return;
#pragma unroll
    for (int s = 0; s < 5; ++s) acc[s * BN + r] = 0.0f;   // zero partial sums

    const float s20 = 20.0f;                    // 1/SIGMA
    float x = points[3*r+0] * s20;
    float y = points[3*r+1] * s20;
    float z = points[3*r+2] * s20;
    float4 v; v.x = x; v.y = y; v.z = z;
    v.w = (x*x + y*y + z*z) * LOG2E;
    xp[r] = v;

    const float4* p1 = (const float4*)(fea1 + (size_t)r * D);
    const float4* p2 = (const float4*)(fea2 + (size_t)r * D);
    float n1 = 0.f, n2 = 0.f;
#pragma unroll
    for (int k = 0; k < D/4; ++k) {
        float4 a = p1[k];
        float4 b = p2[k];
        n1 = fmaf(a.x,a.x, fmaf(a.y,a.y, fmaf(a.z,a.z, fmaf(a.w,a.w, n1))));
        n2 = fmaf(b.x,b.x, fmaf(b.y,b.y, fmaf(b.z,b.z, fmaf(b.w,b.w, n2))));
    }
    f1n[r] = n1 * LOG2E;
    f2n[r] = n2 * LOG2E;
}

// ---------------------------------------------------------------------------
// Kernel A: pair loop. lane = row i; block = 256 rows x one JC j-chunk.
// The j-chunk (fea2 rows, xj, |f2_j|^2) is staged in LDS once, then read with
// wave-uniform addresses -> ds_read broadcasts (conflict-free, LDS pipe).
// All logits are pre-scaled by log2e so exp() is a bare v_exp_f32.
// Shift m=0 is numerically safe: logits <= 0, spatial sum >= 1 (j=i term),
// feature sum's dominant term ~e^{-80} is fp32-normal.
// ---------------------------------------------------------------------------
__global__ __launch_bounds__(BLK) void pair_kernel(
    const float* __restrict__ fea1,
    const float* __restrict__ fea2,
    const float4* __restrict__ xp,
    const float* __restrict__ f1n,
    const float* __restrict__ f2n,
    float* __restrict__ acc,
    int N, int BN)
{
    __shared__ float4 sF2[JC * (D/4)];   // 8 KB: fea2 rows of this chunk
    __shared__ float4 sXJ[JC];           // 1 KB: xp rows of this chunk
    __shared__ float  sCJ[JC];           // 256 B: log2e*|f2_j|^2

    const int nbb = N / BLK;             // i-blocks per batch (uniform)
    const int b   = blockIdx.x / nbb;    // batch index, provably uniform
    const int row = blockIdx.x * BLK + threadIdx.x;
    const int j0  = blockIdx.y * JC;

    // ---- stage the j-chunk (coalesced) ----
    const float4* gF2 = (const float4*)(fea2 + ((size_t)b * N + j0) * D);
    for (int idx = threadIdx.x; idx < JC * (D/4); idx += BLK) sF2[idx] = gF2[idx];
    const float4* gXJ = xp + (size_t)b * N + j0;
    if (threadIdx.x < JC) sXJ[threadIdx.x] = gXJ[threadIdx.x];
    const float* gCJ = f2n + (size_t)b * N + j0;
    if (threadIdx.x < JC) sCJ[threadIdx.x] = gCJ[threadIdx.x];

    // ---- per-lane row state ----
    const float L2 = 2.0f * LOG2E;
    float4 xi = xp[row];
    float xix = xi.x * L2, xiy = xi.y * L2, xiz = xi.z * L2;
    float xiw = xi.w;                    // already log2e-scaled
    float fi  = f1n[row];                // already log2e-scaled

    v2f f1r[D/2];                        // fea1 row pre-scaled by 2*log2e
    const float4* f1v = (const float4*)(fea1 + (size_t)row * D);
#pragma unroll
    for (int k = 0; k < D/4; ++k) {
        float4 t = f1v[k];
        f1r[2*k+0] = (v2f){t.x * L2, t.y * L2};
        f1r[2*k+1] = (v2f){t.z * L2, t.w * L2};
    }
    __syncthreads();

    float sA = 0.f, s2a = 0.f, sB = 0.f, s2b = 0.f, sab = 0.f;

#pragma unroll 4
    for (int jj = 0; jj < JC; ++jj) {
        const float4* fr = &sF2[jj * (D/4)];
        v2f a0 = {0.f, 0.f}, a1 = {0.f, 0.f};
#pragma unroll
        for (int k = 0; k < D/4; ++k) {
            float4 q = fr[k];            // ds_read_b128, wave-uniform broadcast
            v2f qlo = {q.x, q.y};
            v2f qhi = {q.z, q.w};
            a0 = __builtin_elementwise_fma(f1r[2*k+0], qlo, a0);  // v_pk_fma_f32
            a1 = __builtin_elementwise_fma(f1r[2*k+1], qhi, a1);
        }
        v2f as = a0 + a1;
        float dotL = as.x + as.y;        // = 2*log2e * <f1_i, f2_j>

        float4 xj = sXJ[jj];
        float dxL = fmaf(xix, xj.x, fmaf(xiy, xj.y, xiz * xj.z)); // 2*log2e*<xi,xj>

        float aL = dxL - xiw - xj.w;     // log2( spatial kernel )
        float bL = dotL - fi - sCJ[jj];  // log2( feature kernel )

#if __has_builtin(__builtin_amdgcn_exp2f)
        float ea = __builtin_amdgcn_exp2f(aL);
        float eb = __builtin_amdgcn_exp2f(bL);
#else
        float ea = exp2f(aL);
        float eb = exp2f(bL);
#endif
        sA += ea;
        sB += eb;
        s2a = fmaf(ea, ea, s2a);
        s2b = fmaf(eb, eb, s2b);
        sab = fmaf(ea, eb, sab);
    }

    // partial sums -> global (64 chunk-writers per address, spread over 40960)
    atomicAdd(&acc[0*BN + row], sA);
    atomicAdd(&acc[1*BN + row], s2a);
    atomicAdd(&acc[2*BN + row], sB);
    atomicAdd(&acc[3*BN + row], s2b);
    atomicAdd(&acc[4*BN + row], sab);
}

// ---------------------------------------------------------------------------
// Kernel B: combine per-row sums, weight, reduce. 32 blocks; atomics into out
// (zeroed by precompute_kernel).
//   out[b] = sum_i w_i * ( S2a/A^2 - 2*Sab/(A*B) + S2b/B^2 )
// ---------------------------------------------------------------------------
__global__ __launch_bounds__(BLK) void finalize_kernel(
    const float* __restrict__ acc,
    const float* __restrict__ weights,
    float* __restrict__ out,
    int N, int BN)
{
    int row = blockIdx.x * BLK + threadIdx.x;
    int b   = (blockIdx.x * BLK) / N;    // uniform per block (BLK divides N)

    float A   = acc[0*BN + row];
    float S2a = acc[1*BN + row];
    float Bt  = acc[2*BN + row];
    float S2b = acc[3*BN + row];
    float Sab = acc[4*BN + row];
    float invA = 1.0f / A;
    float invB = 1.0f / Bt;
    float val  = S2a*invA*invA - 2.0f*Sab*invA*invB + S2b*invB*invB;
    float sum  = weights[row] * val;

    // wave reduce then cross-wave via LDS
    __shared__ float red[BLK/64];
    for (int off = 32; off > 0; off >>= 1)
        sum += __shfl_down(sum, off);
    if ((threadIdx.x & 63) == 0) red[threadIdx.x >> 6] = sum;
    __syncthreads();
    if (threadIdx.x == 0) {
        float s = 0.f;
#pragma unroll
        for (int w = 0; w < BLK/64; ++w) s += red[w];
        atomicAdd(&out[b], s);
    }
}

// ---------------------------------------------------------------------------
extern "C" void kernel_launch(void* const* d_in, const int* in_sizes, int n_in,
                              void* d_out, int out_size, void* d_ws, size_t ws_size,
                              hipStream_t stream) {
    const float* points  = (const float*)d_in[0];
    const float* fea1    = (const float*)d_in[1];
    const float* fea2    = (const float*)d_in[2];
    const float* weights = (const float*)d_in[3];
    float* out = (float*)d_out;

    int B  = out_size;          // 2
    int BN = in_sizes[3];       // B*N = 8192
    int N  = BN / B;            // 4096

    // workspace layout (floats):
    //   [0, 5*BN)      : acc (A, S2a, B, S2b, Sab)
    //   [5*BN, 9*BN)   : xp (float4/row)
    //   [9*BN, 10*BN)  : f2n
    //   [10*BN, 11*BN) : f1n
    float*  acc = (float*)d_ws;
    float4* xp  = (float4*)((char*)d_ws + (size_t)5  * BN * sizeof(float));
    float*  f2n = (float*)((char*)d_ws + (size_t)9  * BN * sizeof(float));
    float*  f1n = (float*)((char*)d_ws + (size_t)10 * BN * sizeof(float));

    precompute_kernel<<<dim3((BN + BLK - 1) / BLK), dim3(BLK), 0, stream>>>(
        points, fea1, fea2, xp, f1n, f2n, acc, out, BN, B);

    dim3 grid(BN / BLK, N / JC);     // 32 x 64 = 2048 blocks
    pair_kernel<<<grid, dim3(BLK), 0, stream>>>(
        fea1, fea2, xp, f1n, f2n, acc, N, BN);

    finalize_kernel<<<dim3(BN / BLK), dim3(BLK), 0, stream>>>(acc, weights, out, N, BN);
}

// Round 3
// 90.833 us; speedup vs baseline: 2.7383x; 1.1874x over previous
//
#include <hip/hip_runtime.h>

#define D    32       // feature dim (fixed)
#define BLK  256      // threads per block (4 waves, 64 i-rows per block)
#define NCH  8        // j-chunks per batch -> grid.y
#define SJ   128      // j-rows staged in LDS per stage

#define LOG2E 1.44269504088896340736f

typedef short  short8  __attribute__((ext_vector_type(8)));
typedef float  floatx4 __attribute__((ext_vector_type(4)));

__device__ __forceinline__ short f2bf(float v) {       // fp32 -> bf16 (RTNE-ish)
    union { float f; unsigned u; } x; x.f = v;
    unsigned r = x.u + 0x7fffu + ((x.u >> 16) & 1u);
    return (short)(r >> 16);
}
__device__ __forceinline__ float bf2f(short h) {
    union { float f; unsigned u; } x;
    x.u = ((unsigned)(unsigned short)h) << 16;
    return x.f;
}
__device__ __forceinline__ float fast_exp2(float x) {
#if __has_builtin(__builtin_amdgcn_exp2f)
    return __builtin_amdgcn_exp2f(x);
#else
    return exp2f(x);
#endif
}

// ---------------------------------------------------------------------------
// Kernel P: per-row precompute + zero-init of acc and out.
//   xp[r]  = (20*px, 20*py, 20*pz, log2e*|20*p|^2)
//   f1n[r] = log2e*|fea1_r|^2,  f2n[r] = log2e*|fea2_r|^2
// ---------------------------------------------------------------------------
__global__ __launch_bounds__(BLK) void precompute_kernel(
    const float* __restrict__ points,
    const float* __restrict__ fea1,
    const float* __restrict__ fea2,
    float4* __restrict__ xp,
    float* __restrict__ f1n,
    float* __restrict__ f2n,
    float* __restrict__ acc,
    float* __restrict__ out,
    int BN, int Bsz)
{
    int r = blockIdx.x * BLK + threadIdx.x;
    if (r < Bsz) out[r] = 0.0f;
    if (r >= BN) return;
#pragma unroll
    for (int s = 0; s < 5; ++s) acc[s * BN + r] = 0.0f;

    const float s20 = 20.0f;                 // 1/SIGMA
    float x = points[3*r+0] * s20;
    float y = points[3*r+1] * s20;
    float z = points[3*r+2] * s20;
    float4 v; v.x = x; v.y = y; v.z = z;
    v.w = (x*x + y*y + z*z) * LOG2E;
    xp[r] = v;

    const float4* p1 = (const float4*)(fea1 + (size_t)r * D);
    const float4* p2 = (const float4*)(fea2 + (size_t)r * D);
    float n1 = 0.f, n2 = 0.f;
#pragma unroll
    for (int k = 0; k < D/4; ++k) {
        float4 a = p1[k];
        float4 b = p2[k];
        n1 = fmaf(a.x,a.x, fmaf(a.y,a.y, fmaf(a.z,a.z, fmaf(a.w,a.w, n1))));
        n2 = fmaf(b.x,b.x, fmaf(b.y,b.y, fmaf(b.z,b.z, fmaf(b.w,b.w, n2))));
    }
    f1n[r] = n1 * LOG2E;
    f2n[r] = n2 * LOG2E;
}

// ---------------------------------------------------------------------------
// Kernel A: pair loop with MFMA feature dot.
//   Block = 4 waves x 16 i-rows = 64 rows, x one j-chunk of N/NCH.
//   Feature dot <f1_i, f2_j> via split-bf16 MFMA (hi*hi + hi*lo + lo*hi),
//   A = f2 tile (m=j), B = f1 frags (n=i); C: col=lane&15=i, row=quad*4+r=j.
//   Spatial logit stays per-pair fp32 VALU (cancellation-sensitive).
//   f2 chunk is staged in LDS as bf16 hi/lo, converted in-block.
// ---------------------------------------------------------------------------
__global__ __launch_bounds__(BLK) void pair_kernel(
    const float* __restrict__ fea1,
    const float* __restrict__ fea2,
    const float4* __restrict__ xp,
    const float* __restrict__ f1n,
    const float* __restrict__ f2n,
    float* __restrict__ acc,
    int N, int BN)
{
    __shared__ short  sHi[SJ * D];     // 8 KB  f2 hi bf16
    __shared__ short  sLo[SJ * D];     // 8 KB  f2 lo bf16
    __shared__ float4 sXJ[SJ];         // 2 KB  (xj, l2e*|xj|^2)
    __shared__ float  sFN[SJ];         // 512 B l2e*|f2_j|^2

    const int tid  = threadIdx.x;
    const int lane = tid & 63;
    const int wv   = tid >> 6;
    const int m    = lane & 15;        // i-offset (B n-index / C col)
    const int q    = lane >> 4;        // k-octet selector / j-quad

    const int ibpb  = N / 64;          // i-blocks per batch
    const int b     = blockIdx.x / ibpb;
    const int ibase = blockIdx.x * 64 + wv * 16;
    const int JCH   = N / NCH;
    const int jc0   = blockIdx.y * JCH;

    // ---- B fragments: f1 rows of this wave's 16 i's, split hi/lo ----
    const float* f1p = fea1 + (size_t)(ibase + m) * D + q * 8;
    float4 bv0 = *(const float4*)(f1p);
    float4 bv1 = *(const float4*)(f1p + 4);
    float bf[8] = {bv0.x,bv0.y,bv0.z,bv0.w,bv1.x,bv1.y,bv1.z,bv1.w};
    short8 Bhi, Blo;
#pragma unroll
    for (int k = 0; k < 8; ++k) {
        short h = f2bf(bf[k]);
        Bhi[k] = h;
        Blo[k] = f2bf(bf[k] - bf2f(h));
    }

    const float L2 = 2.0f * LOG2E;
    float4 xi = xp[ibase + m];
    float xix = xi.x * L2, xiy = xi.y * L2, xiz = xi.z * L2, xiw = xi.w;
    float nfi = -f1n[ibase + m];       // -log2e*|f1_i|^2

    float sA = 0.f, s2a = 0.f, sB = 0.f, s2b = 0.f, sab = 0.f;

    const float*  f2b  = fea2 + (size_t)(b * N + jc0) * D;
    const float4* xpb  = xp  + (size_t)b * N + jc0;
    const float*  f2nb = f2n + (size_t)b * N + jc0;

    const int rowl = tid >> 3;         // 0..31: staged row within a group
    const int c4   = (tid & 7) * 4;    // float column offset

    for (int s = 0; s < JCH; s += SJ) {
        // ---- stage SJ rows of f2 as bf16 hi/lo (coalesced, conflict-free) ----
#pragma unroll
        for (int g = 0; g < SJ/32; ++g) {
            int r_ = g * 32 + rowl;
            float4 v = *(const float4*)(f2b + (size_t)(s + r_) * D + c4);
            short4 h, l;
            h.x = f2bf(v.x); l.x = f2bf(v.x - bf2f(h.x));
            h.y = f2bf(v.y); l.y = f2bf(v.y - bf2f(h.y));
            h.z = f2bf(v.z); l.z = f2bf(v.z - bf2f(h.z));
            h.w = f2bf(v.w); l.w = f2bf(v.w - bf2f(h.w));
            *(short4*)&sHi[r_ * D + c4] = h;
            *(short4*)&sLo[r_ * D + c4] = l;
        }
        if (tid < SJ) {
            sXJ[tid] = xpb[s + tid];
            sFN[tid] = f2nb[s + tid];
        }
        __syncthreads();

        // ---- compute: 16x16 pair tiles ----
#pragma unroll 2
        for (int jt = 0; jt < SJ; jt += 16) {
            const short8 Ahi = *(const short8*)&sHi[(jt + m) * D + q * 8];
            const short8 Alo = *(const short8*)&sLo[(jt + m) * D + q * 8];
            floatx4 c = {0.f, 0.f, 0.f, 0.f};
            c = __builtin_amdgcn_mfma_f32_16x16x32_bf16(Ahi, Bhi, c, 0, 0, 0);
            c = __builtin_amdgcn_mfma_f32_16x16x32_bf16(Ahi, Blo, c, 0, 0, 0);
            c = __builtin_amdgcn_mfma_f32_16x16x32_bf16(Alo, Bhi, c, 0, 0, 0);
#pragma unroll
            for (int r = 0; r < 4; ++r) {
                int jl = jt + q * 4 + r;
                float4 xj = sXJ[jl];
                float bL = fmaf(c[r], L2, nfi - sFN[jl]);   // log2 feature kernel
                float aL = fmaf(xiz, xj.z,
                            fmaf(xiy, xj.y,
                             fmaf(xix, xj.x, -xiw))) - xj.w; // log2 spatial kernel
                float ea = fast_exp2(aL);
                float eb = fast_exp2(bL);
                sA += ea;
                sB += eb;
                s2a = fmaf(ea, ea, s2a);
                s2b = fmaf(eb, eb, s2b);
                sab = fmaf(ea, eb, sab);
            }
        }
        __syncthreads();
    }

    // ---- reduce the 4 j-quads (lanes sharing lane&15) ----
    sA  += __shfl_xor(sA, 16);  sA  += __shfl_xor(sA, 32);
    s2a += __shfl_xor(s2a, 16); s2a += __shfl_xor(s2a, 32);
    sB  += __shfl_xor(sB, 16);  sB  += __shfl_xor(sB, 32);
    s2b += __shfl_xor(s2b, 16); s2b += __shfl_xor(s2b, 32);
    sab += __shfl_xor(sab, 16); sab += __shfl_xor(sab, 32);

    if (lane < 16) {
        int row = ibase + lane;
        atomicAdd(&acc[0*BN + row], sA);
        atomicAdd(&acc[1*BN + row], s2a);
        atomicAdd(&acc[2*BN + row], sB);
        atomicAdd(&acc[3*BN + row], s2b);
        atomicAdd(&acc[4*BN + row], sab);
    }
}

// ---------------------------------------------------------------------------
// Kernel B: combine per-row sums, weight, reduce into out[b] (out zeroed by P).
// ---------------------------------------------------------------------------
__global__ __launch_bounds__(BLK) void finalize_kernel(
    const float* __restrict__ acc,
    const float* __restrict__ weights,
    float* __restrict__ out,
    int N, int BN)
{
    int row = blockIdx.x * BLK + threadIdx.x;
    int b   = (blockIdx.x * BLK) / N;

    float A   = acc[0*BN + row];
    float S2a = acc[1*BN + row];
    float Bt  = acc[2*BN + row];
    float S2b = acc[3*BN + row];
    float Sab = acc[4*BN + row];
    float invA = 1.0f / A;
    float invB = 1.0f / Bt;
    float val  = S2a*invA*invA - 2.0f*Sab*invA*invB + S2b*invB*invB;
    float sum  = weights[row] * val;

    __shared__ float red[BLK/64];
    for (int off = 32; off > 0; off >>= 1)
        sum += __shfl_down(sum, off);
    if ((threadIdx.x & 63) == 0) red[threadIdx.x >> 6] = sum;
    __syncthreads();
    if (threadIdx.x == 0) {
        float s = 0.f;
#pragma unroll
        for (int w = 0; w < BLK/64; ++w) s += red[w];
        atomicAdd(&out[b], s);
    }
}

// ---------------------------------------------------------------------------
extern "C" void kernel_launch(void* const* d_in, const int* in_sizes, int n_in,
                              void* d_out, int out_size, void* d_ws, size_t ws_size,
                              hipStream_t stream) {
    const float* points  = (const float*)d_in[0];
    const float* fea1    = (const float*)d_in[1];
    const float* fea2    = (const float*)d_in[2];
    const float* weights = (const float*)d_in[3];
    float* out = (float*)d_out;

    int B  = out_size;          // 2
    int BN = in_sizes[3];       // B*N = 8192
    int N  = BN / B;            // 4096

    // workspace (floats): acc[5*BN] | xp[4*BN] | f2n[BN] | f1n[BN]
    float*  acc = (float*)d_ws;
    float4* xp  = (float4*)((char*)d_ws + (size_t)5  * BN * sizeof(float));
    float*  f2n = (float*)((char*)d_ws + (size_t)9  * BN * sizeof(float));
    float*  f1n = (float*)((char*)d_ws + (size_t)10 * BN * sizeof(float));

    precompute_kernel<<<dim3((BN + BLK - 1) / BLK), dim3(BLK), 0, stream>>>(
        points, fea1, fea2, xp, f1n, f2n, acc, out, BN, B);

    dim3 grid(BN / 64, NCH);    // 128 x 8 = 1024 blocks
    pair_kernel<<<grid, dim3(BLK), 0, stream>>>(
        fea1, fea2, xp, f1n, f2n, acc, N, BN);

    finalize_kernel<<<dim3(BN / BLK), dim3(BLK), 0, stream>>>(acc, weights, out, N, BN);
}

// Round 4
// 86.042 us; speedup vs baseline: 2.8908x; 1.0557x over previous
//
#include <hip/hip_runtime.h>

#define D    32       // feature dim (fixed)
#define BLK  256      // threads per block (4 waves, 64 i-rows per block)
#define NCH  16       // j-chunks per batch -> grid.y
#define SJ   128      // j-rows staged in LDS per stage (8 MFMA tiles)

#define LOG2E 1.44269504088896340736f

typedef short  short8  __attribute__((ext_vector_type(8)));
typedef float  floatx4 __attribute__((ext_vector_type(4)));
typedef float  v2f     __attribute__((ext_vector_type(2)));

__device__ __forceinline__ short f2bf(float v) {       // fp32 -> bf16 (RTNE-ish)
    union { float f; unsigned u; } x; x.f = v;
    unsigned r = x.u + 0x7fffu + ((x.u >> 16) & 1u);
    return (short)(r >> 16);
}
__device__ __forceinline__ float bf2f(short h) {
    union { float f; unsigned u; } x;
    x.u = ((unsigned)(unsigned short)h) << 16;
    return x.f;
}
__device__ __forceinline__ float fast_exp2(float x) {
#if __has_builtin(__builtin_amdgcn_exp2f)
    return __builtin_amdgcn_exp2f(x);
#else
    return exp2f(x);
#endif
}

// ---------------------------------------------------------------------------
// Kernel P: per-row precompute + zero-init + global bf16 hi/lo split of fea2
// stored FRAGMENT-MAJOR: for row n (tile t=n/16, m=n%16), k-octet q, the
// 8 bf16 go to slot l=m+16q of tile t:  gX[(t*64 + l)*8 .. +8).
// This makes both the pair-kernel staging copy and the per-lane A-fragment
// ds_read lane-contiguous (zero bank conflicts, minimal LDS cycles).
//   xp[r]  = (20*px, 20*py, 20*pz, log2e*|20*p|^2)
//   f1n[r] = log2e*|fea1_r|^2,  f2n[r] = log2e*|fea2_r|^2
// ---------------------------------------------------------------------------
__global__ __launch_bounds__(BLK) void precompute_kernel(
    const float* __restrict__ points,
    const float* __restrict__ fea1,
    const float* __restrict__ fea2,
    float4* __restrict__ xp,
    float* __restrict__ f1n,
    float* __restrict__ f2n,
    short* __restrict__ f2hi,
    short* __restrict__ f2lo,
    float* __restrict__ acc,
    float* __restrict__ out,
    int BN, int Bsz)
{
    int r = blockIdx.x * BLK + threadIdx.x;
    if (r < Bsz) out[r] = 0.0f;
    if (r >= BN) return;
#pragma unroll
    for (int s = 0; s < 5; ++s) acc[s * BN + r] = 0.0f;

    const float s20 = 20.0f;                 // 1/SIGMA
    float x = points[3*r+0] * s20;
    float y = points[3*r+1] * s20;
    float z = points[3*r+2] * s20;
    float4 v; v.x = x; v.y = y; v.z = z;
    v.w = (x*x + y*y + z*z) * LOG2E;
    xp[r] = v;

    // f1 norm
    const float4* p1 = (const float4*)(fea1 + (size_t)r * D);
    float n1 = 0.f;
#pragma unroll
    for (int k = 0; k < D/4; ++k) {
        float4 a = p1[k];
        n1 = fmaf(a.x,a.x, fmaf(a.y,a.y, fmaf(a.z,a.z, fmaf(a.w,a.w, n1))));
    }
    f1n[r] = n1 * LOG2E;

    // f2: norm + hi/lo split, scattered fragment-major
    const int t = r >> 4;                    // global 16-row tile id
    const int m = r & 15;
    const float* p2 = fea2 + (size_t)r * D;
    float n2 = 0.f;
#pragma unroll
    for (int q = 0; q < 4; ++q) {
        float4 v0 = *(const float4*)(p2 + q*8);
        float4 v1 = *(const float4*)(p2 + q*8 + 4);
        float e[8] = {v0.x,v0.y,v0.z,v0.w,v1.x,v1.y,v1.z,v1.w};
        short8 h, l;
#pragma unroll
        for (int k = 0; k < 8; ++k) {
            n2 = fmaf(e[k], e[k], n2);
            short hh = f2bf(e[k]);
            h[k] = hh;
            l[k] = f2bf(e[k] - bf2f(hh));
        }
        size_t off = ((size_t)t * 64 + m + 16*q) * 8;
        *(short8*)&f2hi[off] = h;
        *(short8*)&f2lo[off] = l;
    }
    f2n[r] = n2 * LOG2E;
}

// ---------------------------------------------------------------------------
// Kernel A: pair loop with MFMA feature dot (split-bf16: hi*hi+hi*lo+lo*hi).
//   Block = 4 waves x 16 i-rows = 64 rows, x one j-chunk of N/NCH.
//   f2 hi/lo arrive pre-split, fragment-major -> staging is a pure uint4
//   copy (contiguous->contiguous); A-fragment reads are lane-contiguous
//   ds_read_b128 (structural-minimum LDS cycles, zero conflicts).
//   Spatial logit per-pair fp32 VALU (cancellation-sensitive, keeps absmax 0).
// ---------------------------------------------------------------------------
__global__ __launch_bounds__(BLK) void pair_kernel(
    const float* __restrict__ fea1,
    const short* __restrict__ f2hi,
    const short* __restrict__ f2lo,
    const float4* __restrict__ xp,
    const float* __restrict__ f1n,
    const float* __restrict__ f2n,
    float* __restrict__ acc,
    int N, int BN)
{
    __shared__ __align__(16) short sHi[SJ * D];   // 8 KB, fragment-major
    __shared__ __align__(16) short sLo[SJ * D];   // 8 KB
    __shared__ float4 sXJ[SJ];                    // 2 KB
    __shared__ float  sFN[SJ];                    // 512 B

    const int tid  = threadIdx.x;
    const int lane = tid & 63;
    const int wv   = tid >> 6;
    const int m    = lane & 15;        // i-offset (B n-index / C col)
    const int q    = lane >> 4;        // k-octet / j-quad

    const int ibpb  = N / 64;          // i-blocks per batch
    const int b     = blockIdx.x / ibpb;
    const int ibase = blockIdx.x * 64 + wv * 16;
    const int JCH   = N / NCH;
    const int jc0   = blockIdx.y * JCH;

    // ---- B fragments: f1 rows of this wave's 16 i's, split hi/lo ----
    const float* f1p = fea1 + (size_t)(ibase + m) * D + q * 8;
    float4 bv0 = *(const float4*)(f1p);
    float4 bv1 = *(const float4*)(f1p + 4);
    float bf[8] = {bv0.x,bv0.y,bv0.z,bv0.w,bv1.x,bv1.y,bv1.z,bv1.w};
    short8 Bhi, Blo;
#pragma unroll
    for (int k = 0; k < 8; ++k) {
        short h = f2bf(bf[k]);
        Bhi[k] = h;
        Blo[k] = f2bf(bf[k] - bf2f(h));
    }

    const float L2 = 2.0f * LOG2E;
    float4 xi = xp[ibase + m];
    float xix = xi.x * L2, xiy = xi.y * L2, xiz = xi.z * L2;
    float mxiw = -xi.w;
    float nfi  = -f1n[ibase + m];      // -log2e*|f1_i|^2

    v2f sAB = {0.f, 0.f};              // (sum e^a, sum e^b)
    v2f s2  = {0.f, 0.f};              // (sum e^2a, sum e^2b)
    float sab = 0.f;                   // sum e^a e^b

    const short*  gHi  = f2hi + ((size_t)(b * N + jc0) >> 4) * 512;
    const short*  gLo  = f2lo + ((size_t)(b * N + jc0) >> 4) * 512;
    const float4* xpb  = xp  + (size_t)b * N + jc0;
    const float*  f2nb = f2n + (size_t)b * N + jc0;

    for (int s = 0; s < JCH; s += SJ) {
        // ---- stage: pure contiguous copy (8 KB hi + 8 KB lo) ----
        const uint4* srcH = (const uint4*)(gHi + (size_t)(s >> 4) * 512);
        const uint4* srcL = (const uint4*)(gLo + (size_t)(s >> 4) * 512);
        uint4* dstH = (uint4*)sHi;
        uint4* dstL = (uint4*)sLo;
        dstH[tid]       = srcH[tid];
        dstH[tid + 256] = srcH[tid + 256];
        dstL[tid]       = srcL[tid];
        dstL[tid + 256] = srcL[tid + 256];
        if (tid < SJ) {
            sXJ[tid] = xpb[s + tid];
            sFN[tid] = f2nb[s + tid];
        }
        __syncthreads();

        // ---- compute: 8 16x16 pair tiles ----
#pragma unroll 2
        for (int jt8 = 0; jt8 < SJ/16; ++jt8) {
            const short8 Ahi = *(const short8*)&sHi[(jt8 * 64 + lane) * 8];
            const short8 Alo = *(const short8*)&sLo[(jt8 * 64 + lane) * 8];
            floatx4 c = {0.f, 0.f, 0.f, 0.f};
            c = __builtin_amdgcn_mfma_f32_16x16x32_bf16(Ahi, Bhi, c, 0, 0, 0);
            c = __builtin_amdgcn_mfma_f32_16x16x32_bf16(Ahi, Blo, c, 0, 0, 0);
            c = __builtin_amdgcn_mfma_f32_16x16x32_bf16(Alo, Bhi, c, 0, 0, 0);
#pragma unroll
            for (int r = 0; r < 4; ++r) {
                int jl = jt8 * 16 + q * 4 + r;
                float4 xj = sXJ[jl];
                float bL = fmaf(c[r], L2, nfi - sFN[jl]);       // log2 feature
                float aL = fmaf(xiz, xj.z,
                             fmaf(xiy, xj.y,
                              fmaf(xix, xj.x, mxiw))) - xj.w;   // log2 spatial
                float ea = fast_exp2(aL);
                float eb = fast_exp2(bL);
                v2f e = {ea, eb};
                sAB += e;                                   // v_pk_add_f32
                s2   = __builtin_elementwise_fma(e, e, s2); // v_pk_fma_f32
                sab  = fmaf(ea, eb, sab);
            }
        }
        __syncthreads();
    }

    // ---- reduce the 4 j-quads (lanes sharing lane&15) ----
    float vA = sAB.x, vB = sAB.y, v2a = s2.x, v2b = s2.y;
    vA  += __shfl_xor(vA, 16);  vA  += __shfl_xor(vA, 32);
    vB  += __shfl_xor(vB, 16);  vB  += __shfl_xor(vB, 32);
    v2a += __shfl_xor(v2a, 16); v2a += __shfl_xor(v2a, 32);
    v2b += __shfl_xor(v2b, 16); v2b += __shfl_xor(v2b, 32);
    sab += __shfl_xor(sab, 16); sab += __shfl_xor(sab, 32);

    if (lane < 16) {
        int row = ibase + lane;
        atomicAdd(&acc[0*BN + row], vA);
        atomicAdd(&acc[1*BN + row], v2a);
        atomicAdd(&acc[2*BN + row], vB);
        atomicAdd(&acc[3*BN + row], v2b);
        atomicAdd(&acc[4*BN + row], sab);
    }
}

// ---------------------------------------------------------------------------
// Kernel B: combine per-row sums, weight, reduce into out[b] (out zeroed by P).
//   out[b] = sum_i w_i * ( S2a/A^2 - 2*Sab/(A*B) + S2b/B^2 )
// ---------------------------------------------------------------------------
__global__ __launch_bounds__(BLK) void finalize_kernel(
    const float* __restrict__ acc,
    const float* __restrict__ weights,
    float* __restrict__ out,
    int N, int BN)
{
    int row = blockIdx.x * BLK + threadIdx.x;
    int b   = (blockIdx.x * BLK) / N;

    float A   = acc[0*BN + row];
    float S2a = acc[1*BN + row];
    float Bt  = acc[2*BN + row];
    float S2b = acc[3*BN + row];
    float Sab = acc[4*BN + row];
    float invA = 1.0f / A;
    float invB = 1.0f / Bt;
    float val  = S2a*invA*invA - 2.0f*Sab*invA*invB + S2b*invB*invB;
    float sum  = weights[row] * val;

    __shared__ float red[BLK/64];
    for (int off = 32; off > 0; off >>= 1)
        sum += __shfl_down(sum, off);
    if ((threadIdx.x & 63) == 0) red[threadIdx.x >> 6] = sum;
    __syncthreads();
    if (threadIdx.x == 0) {
        float s = 0.f;
#pragma unroll
        for (int w = 0; w < BLK/64; ++w) s += red[w];
        atomicAdd(&out[b], s);
    }
}

// ---------------------------------------------------------------------------
extern "C" void kernel_launch(void* const* d_in, const int* in_sizes, int n_in,
                              void* d_out, int out_size, void* d_ws, size_t ws_size,
                              hipStream_t stream) {
    const float* points  = (const float*)d_in[0];
    const float* fea1    = (const float*)d_in[1];
    const float* fea2    = (const float*)d_in[2];
    const float* weights = (const float*)d_in[3];
    float* out = (float*)d_out;

    int B  = out_size;          // 2
    int BN = in_sizes[3];       // B*N = 8192
    int N  = BN / B;            // 4096

    // workspace (bytes):
    //   acc   : 5*BN*4          @ 0
    //   xp    : 4*BN*4          @ 5*BN*4
    //   f2n   : BN*4            @ 9*BN*4
    //   f1n   : BN*4            @ 10*BN*4
    //   f2hi  : BN*D*2          @ 11*BN*4
    //   f2lo  : BN*D*2          @ 11*BN*4 + BN*D*2
    float*  acc  = (float*)d_ws;
    float4* xp   = (float4*)((char*)d_ws + (size_t)5  * BN * 4);
    float*  f2n  = (float*)((char*)d_ws + (size_t)9  * BN * 4);
    float*  f1n  = (float*)((char*)d_ws + (size_t)10 * BN * 4);
    short*  f2hi = (short*)((char*)d_ws + (size_t)11 * BN * 4);
    short*  f2lo = f2hi + (size_t)BN * D;

    precompute_kernel<<<dim3((BN + BLK - 1) / BLK), dim3(BLK), 0, stream>>>(
        points, fea1, fea2, xp, f1n, f2n, f2hi, f2lo, acc, out, BN, B);

    dim3 grid(BN / 64, NCH);    // 128 x 16 = 2048 blocks (8 blocks/CU)
    pair_kernel<<<grid, dim3(BLK), 0, stream>>>(
        fea1, f2hi, f2lo, xp, f1n, f2n, acc, N, BN);

    finalize_kernel<<<dim3(BN / BLK), dim3(BLK), 0, stream>>>(acc, weights, out, N, BN);
}